// Round 7
// baseline (967.361 us; speedup 1.0000x reference)
//
#include <hip/hip_runtime.h>
#include <math.h>

typedef unsigned short ushort;
typedef __attribute__((ext_vector_type(8))) short short8v;
typedef __attribute__((ext_vector_type(4))) short short4v;
typedef __attribute__((ext_vector_type(4))) float float4v;
typedef __attribute__((ext_vector_type(8))) __bf16 bf16x8;

#define NHEADS 8
#define NPOS 3136
#define MROWS 50176          // 16*3136
#define KDIM 512

__device__ __forceinline__ ushort f2bf(float f) {
  union { float f; unsigned u; } x; x.f = f;
  unsigned r = x.u + 0x7fffu + ((x.u >> 16) & 1u);
  return (ushort)(r >> 16);
}
__device__ __forceinline__ float bf2f(ushort h) {
  union { unsigned u; float f; } x; x.u = ((unsigned)h) << 16; return x.f;
}

__device__ __forceinline__ float4v mfma16(short8v a, short8v b, float4v c) {
  return __builtin_amdgcn_mfma_f32_16x16x32_bf16(
      __builtin_bit_cast(bf16x8, a), __builtin_bit_cast(bf16x8, b), c, 0, 0, 0);
}

__device__ __forceinline__ void glds16(const void* g, void* l) {
  __builtin_amdgcn_global_load_lds(
      (const __attribute__((address_space(1))) unsigned int*)g,
      (__attribute__((address_space(3))) unsigned int*)l, 16, 0, 0);
}

// ---------------- prep: scale_inv, power ----------------
__global__ __launch_bounds__(512) void prep_kernel(const float* __restrict__ scale_p,
                                                   const float* __restrict__ power_p,
                                                   float* __restrict__ scinv,
                                                   float* __restrict__ pwr)
{
  int t = threadIdx.x;
  if (t < KDIM) {
    scinv[t] = 1.f / log1pf(expf(scale_p[t]));
    pwr[t]   = 1.f + 4.f / (1.f + expf(-power_p[t]));
  }
}

// ---------------- x fp32 -> bf16 ----------------
__global__ __launch_bounds__(256) void cvt_x_kernel(const float* __restrict__ x,
                                                    ushort* __restrict__ xb)
{
  const size_t i = ((size_t)blockIdx.x * 256 + threadIdx.x) * 4;
  float4v v = *(const float4v*)(x + i);
  short4v o = { (short)f2bf(v[0]), (short)f2bf(v[1]), (short)f2bf(v[2]), (short)f2bf(v[3]) };
  *(short4v*)(xb + i) = o;
}

// ---------------- weight transpose fp32[K][N] -> bf16[N][K] ----------------
__global__ __launch_bounds__(256) void transpose_w_kernel(const float* __restrict__ src,
                                                          ushort* __restrict__ dst,
                                                          int K, int N)
{
  __shared__ float tile[32][33];
  const int t = threadIdx.x, tx = t & 31, ty = t >> 5;
  const int nb = blockIdx.x * 32, kb = blockIdx.y * 32;
  #pragma unroll
  for (int i = 0; i < 4; i++)
    tile[ty + i*8][tx] = src[(size_t)(kb + ty + i*8) * N + nb + tx];
  __syncthreads();
  #pragma unroll
  for (int i = 0; i < 4; i++)
    dst[(size_t)(nb + ty + i*8) * K + kb + tx] = f2bf(tile[tx][ty + i*8]);
}

// ------------- fused feature GEMM: N=2048 (k|v|q|g sections), raw outputs ----
// A bf16 [M][512]; Bt bf16 [2048][512]. Each 128-wide n-block lies in one section.
__global__ __launch_bounds__(256) void gemm_feat_kernel(
    const ushort* __restrict__ A, const ushort* __restrict__ Bt,
    const float* __restrict__ scinv, const float* __restrict__ pos_enc,
    ushort* __restrict__ khm, ushort* __restrict__ vhm,
    ushort* __restrict__ qhm, ushort* __restrict__ gbuf)
{
  __shared__ ushort As[2][128*32];
  __shared__ ushort Bs[2][128*32];
  const int t = threadIdx.x;
  const int wave = t >> 6, lane = t & 63;
  const int m0 = blockIdx.y * 128, n0 = blockIdx.x * 128;
  const int wm = wave >> 1, wn = wave & 1;
  const int rA = lane >> 2;
  const int kc = (lane & 3) * 8;
  const int ra0 = wave*32, ra1 = wave*32 + 16;

  float4v acc[4][4];
  #pragma unroll
  for (int i = 0; i < 4; i++)
    #pragma unroll
    for (int j = 0; j < 4; j++) { float4v z = {0.f,0.f,0.f,0.f}; acc[i][j] = z; }

  glds16(A  + (size_t)(m0 + ra0 + rA)*KDIM + kc, &As[0][ra0*32]);
  glds16(Bt + (size_t)(n0 + ra0 + rA)*KDIM + kc, &Bs[0][ra0*32]);
  glds16(A  + (size_t)(m0 + ra1 + rA)*KDIM + kc, &As[0][ra1*32]);
  glds16(Bt + (size_t)(n0 + ra1 + rA)*KDIM + kc, &Bs[0][ra1*32]);
  __syncthreads();

  const int lm = lane & 15, q8 = (lane >> 4) * 8;

  for (int k0 = 0; k0 < KDIM; k0 += 32) {
    const int cur = (k0 >> 5) & 1;
    if (k0 + 32 < KDIM) {
      const int nxt = cur ^ 1;
      const int kn = k0 + 32;
      glds16(A  + (size_t)(m0 + ra0 + rA)*KDIM + kn + kc, &As[nxt][ra0*32]);
      glds16(Bt + (size_t)(n0 + ra0 + rA)*KDIM + kn + kc, &Bs[nxt][ra0*32]);
      glds16(A  + (size_t)(m0 + ra1 + rA)*KDIM + kn + kc, &As[nxt][ra1*32]);
      glds16(Bt + (size_t)(n0 + ra1 + rA)*KDIM + kn + kc, &Bs[nxt][ra1*32]);
    }
    const ushort* Asc = As[cur];
    const ushort* Bsc = Bs[cur];
    short8v a[4], b[4];
    #pragma unroll
    for (int i = 0; i < 4; i++) {
      a[i] = *(const short8v*)&Asc[(wm*64 + i*16 + lm)*32 + q8];
      b[i] = *(const short8v*)&Bsc[(wn*64 + i*16 + lm)*32 + q8];
    }
    #pragma unroll
    for (int i = 0; i < 4; i++)
      #pragma unroll
      for (int j = 0; j < 4; j++)
        acc[i][j] = mfma16(a[i], b[j], acc[i][j]);
    __syncthreads();
  }

  const int sec = n0 >> 9;          // 0:k 1:v 2:q 3:g
  const int cbase = n0 & 511;
  const int rq = (lane >> 4) * 4;
  int bbv[16], nnv[16];
  #pragma unroll
  for (int i = 0; i < 4; i++)
    #pragma unroll
    for (int r = 0; r < 4; r++) {
      const int grow = m0 + wm*64 + i*16 + rq + r;
      const int bb = grow / NPOS;
      bbv[i*4+r] = bb; nnv[i*4+r] = grow - bb*NPOS;
    }
  #pragma unroll
  for (int j = 0; j < 4; j++) {
    const int c = cbase + wn*64 + j*16 + lm;
    const int h = c >> 6, d = c & 63;
    const float sc = scinv[c];
    #pragma unroll
    for (int i = 0; i < 4; i++)
      #pragma unroll
      for (int r = 0; r < 4; r++) {
        const float val = acc[i][j][r];
        const int bb = bbv[i*4+r], nn = nnv[i*4+r];
        const size_t hm = (((size_t)(bb*8 + h)*NPOS + nn) << 6) + d;
        if (sec == 0)      khm[hm] = f2bf((val + pos_enc[(size_t)nn*512 + c]) * sc);
        else if (sec == 1) vhm[hm] = f2bf(val);
        else if (sec == 2) qhm[hm] = f2bf(val * sc);
        else               gbuf[((size_t)bb*NPOS + nn)*512 + c] = f2bf(val);
      }
  }
}

// ---------------- proj GEMM: out fp32 + bias ----------------
__global__ __launch_bounds__(256) void gemm_proj_kernel(
    const ushort* __restrict__ A, const ushort* __restrict__ Bt,
    const float* __restrict__ bias, float* __restrict__ outf)
{
  __shared__ ushort As[2][128*32];
  __shared__ ushort Bs[2][128*32];
  const int t = threadIdx.x;
  const int wave = t >> 6, lane = t & 63;
  const int m0 = blockIdx.y * 128, n0 = blockIdx.x * 128;
  const int wm = wave >> 1, wn = wave & 1;
  const int rA = lane >> 2;
  const int kc = (lane & 3) * 8;
  const int ra0 = wave*32, ra1 = wave*32 + 16;

  float4v acc[4][4];
  #pragma unroll
  for (int i = 0; i < 4; i++)
    #pragma unroll
    for (int j = 0; j < 4; j++) { float4v z = {0.f,0.f,0.f,0.f}; acc[i][j] = z; }

  glds16(A  + (size_t)(m0 + ra0 + rA)*KDIM + kc, &As[0][ra0*32]);
  glds16(Bt + (size_t)(n0 + ra0 + rA)*KDIM + kc, &Bs[0][ra0*32]);
  glds16(A  + (size_t)(m0 + ra1 + rA)*KDIM + kc, &As[0][ra1*32]);
  glds16(Bt + (size_t)(n0 + ra1 + rA)*KDIM + kc, &Bs[0][ra1*32]);
  __syncthreads();

  const int lm = lane & 15, q8 = (lane >> 4) * 8;

  for (int k0 = 0; k0 < KDIM; k0 += 32) {
    const int cur = (k0 >> 5) & 1;
    if (k0 + 32 < KDIM) {
      const int nxt = cur ^ 1;
      const int kn = k0 + 32;
      glds16(A  + (size_t)(m0 + ra0 + rA)*KDIM + kn + kc, &As[nxt][ra0*32]);
      glds16(Bt + (size_t)(n0 + ra0 + rA)*KDIM + kn + kc, &Bs[nxt][ra0*32]);
      glds16(A  + (size_t)(m0 + ra1 + rA)*KDIM + kn + kc, &As[nxt][ra1*32]);
      glds16(Bt + (size_t)(n0 + ra1 + rA)*KDIM + kn + kc, &Bs[nxt][ra1*32]);
    }
    const ushort* Asc = As[cur];
    const ushort* Bsc = Bs[cur];
    short8v a[4], b[4];
    #pragma unroll
    for (int i = 0; i < 4; i++) {
      a[i] = *(const short8v*)&Asc[(wm*64 + i*16 + lm)*32 + q8];
      b[i] = *(const short8v*)&Bsc[(wn*64 + i*16 + lm)*32 + q8];
    }
    #pragma unroll
    for (int i = 0; i < 4; i++)
      #pragma unroll
      for (int j = 0; j < 4; j++)
        acc[i][j] = mfma16(a[i], b[j], acc[i][j]);
    __syncthreads();
  }

  const int rq = (lane >> 4) * 4;
  #pragma unroll
  for (int i = 0; i < 4; i++)
    #pragma unroll
    for (int r = 0; r < 4; r++) {
      const int grow = m0 + wm*64 + i*16 + rq + r;
      #pragma unroll
      for (int j = 0; j < 4; j++) {
        const int gcol = n0 + wn*64 + j*16 + lm;
        outf[(size_t)grow * 512 + gcol] = acc[i][j][r] + bias[gcol];
      }
    }
}

// ------- kf outer-product partial reduction (features computed in-kernel) ----
#define RSPLIT 4
#define RCHUNK 784
__global__ __launch_bounds__(256) void reduce_kv_kernel(
    const ushort* __restrict__ khm, const ushort* __restrict__ vhm,
    const float* __restrict__ pwr,
    float* __restrict__ pkv, float* __restrict__ pkm)
{
  const int bh = blockIdx.x >> 2, s = blockIdx.x & 3;
  const int h = bh & 7;
  const int t = threadIdx.x;
  __shared__ ushort kf_s[8*128];
  __shared__ ushort v_s[8*64];
  __shared__ float pwr_s[64];
  if (t < 64) pwr_s[t] = pwr[h*64 + t];
  __syncthreads();

  const int td = t & 31, te = t >> 5;
  const int d4 = td * 4, e8 = te * 8;
  float acc[4][8];
  #pragma unroll
  for (int c = 0; c < 4; c++)
    #pragma unroll
    for (int e = 0; e < 8; e++) acc[c][e] = 0.f;
  float km4[4] = {0.f,0.f,0.f,0.f};
  const int nbase = s * RCHUNK;

  for (int g = 0; g < RCHUNK/8; g++) {
    const int n = nbase + g*8;
    // compute kf features (interleaved f=2d+s) for 8 rows
    #pragma unroll
    for (int u = 0; u < 2; u++) {
      const int idx = u*256 + t;           // 0..511
      const int row = idx >> 6, d = idx & 63;
      const float kk = bf2f(khm[(((size_t)bh*NPOS + n + row) << 6) + d]);
      const float p = pwr_s[d];
      const float aq = fabsf(kk);
      float f = 0.f;
      if (aq > 0.f) f = exp2f(p * log2f(aq));
      const unsigned fb = (unsigned)f2bf(f);
      unsigned pack = 0;
      if (kk > 0.f)      pack = fb;
      else if (kk < 0.f) pack = fb << 16;
      *(unsigned*)&kf_s[row*128 + 2*d] = pack;
    }
    if (t < 128)
      *(short4v*)&v_s[(t>>4)*64 + (t&15)*4] =
          *(const short4v*)&vhm[(((size_t)bh*NPOS + n + (t>>4)) << 6) + (t&15)*4];
    __syncthreads();
    #pragma unroll
    for (int i = 0; i < 8; i++) {
      short4v k4 = *(const short4v*)&kf_s[i*128 + d4];
      short8v v8 = *(const short8v*)&v_s[i*64 + e8];
      float kf4[4], vf[8];
      #pragma unroll
      for (int c = 0; c < 4; c++) kf4[c] = bf2f((ushort)k4[c]);
      #pragma unroll
      for (int e = 0; e < 8; e++) vf[e] = bf2f((ushort)v8[e]);
      if (te == 0) {
        #pragma unroll
        for (int c = 0; c < 4; c++) km4[c] += kf4[c];
      }
      #pragma unroll
      for (int c = 0; c < 4; c++)
        #pragma unroll
        for (int e = 0; e < 8; e++) acc[c][e] = fmaf(kf4[c], vf[e], acc[c][e]);
    }
    __syncthreads();
  }
  float* op = pkv + ((size_t)(s*128 + bh) << 13);
  #pragma unroll
  for (int c = 0; c < 4; c++) {
    float4v o0 = {acc[c][0], acc[c][1], acc[c][2], acc[c][3]};
    float4v o1 = {acc[c][4], acc[c][5], acc[c][6], acc[c][7]};
    *(float4v*)&op[(d4+c)*64 + e8]     = o0;
    *(float4v*)&op[(d4+c)*64 + e8 + 4] = o1;
  }
  if (te == 0) {
    #pragma unroll
    for (int c = 0; c < 4; c++) pkm[((size_t)(s*128 + bh) << 7) + d4 + c] = km4[c];
  }
}

// ---------------- final reduce -> kvf2^T bf16 [bh][80][128] ----------------
__global__ __launch_bounds__(256) void reduce_final_kernel(
    const float* __restrict__ pkv, const float* __restrict__ pkm,
    ushort* __restrict__ Kt)
{
  const int bh = blockIdx.x, t = threadIdx.x;
  const float inv_n = 1.f / (float)NPOS;
  for (int i = t; i < 8192; i += 256) {
    float s = 0.f;
    #pragma unroll
    for (int sp = 0; sp < RSPLIT; sp++) s += pkv[((size_t)(sp*128 + bh) << 13) + i];
    const int d = i >> 6, e = i & 63;
    const int dd = (e < 32) ? d : (d ^ 1);
    Kt[((size_t)bh*80 + e)*128 + dd] = f2bf(s * inv_n);
  }
  if (t < 128) {
    float s = 0.f;
    #pragma unroll
    for (int sp = 0; sp < RSPLIT; sp++) s += pkm[((size_t)(sp*128 + bh) << 7) + t];
    const ushort b = f2bf(s * inv_n);
    Kt[((size_t)bh*80 + 64)*128 + t] = b;          // km (denom_sim)
    Kt[((size_t)bh*80 + 65)*128 + (t ^ 1)] = b;    // km swapped (denom_opp)
  }
  for (int i = t; i < 14*128; i += 256) Kt[((size_t)bh*80 + 66)*128 + i] = 0;
}

// ------- attention apply: features from raw q built in-register -> MFMA -----
__global__ __launch_bounds__(256) void attn_mfma_kernel(
    const ushort* __restrict__ qhm, const ushort* __restrict__ Kt,
    const float* __restrict__ pwr, ushort* __restrict__ XO)
{
  __shared__ ushort q_s[128*68];    // stride 68: breaks bank conflicts
  __shared__ ushort kv_s[80*128];
  __shared__ float pwr_s[64];
  const int t = threadIdx.x, wave = t >> 6, lane = t & 63;
  const int bh = blockIdx.y, h = bh & 7;
  const int n0 = blockIdx.x * 128;

  const ushort* ksrc = Kt + (size_t)bh * 80 * 128;
  #pragma unroll
  for (int j = 0; j < 5; j++) {
    const int elem = (j*4096 + wave*1024) >> 1;
    glds16(ksrc + elem + lane*8, kv_s + elem);
  }
  const ushort* qsrc = qhm + ((size_t)bh * NPOS + n0) * 64;
  #pragma unroll
  for (int u = 0; u < 8; u++) {
    const int idx = u*256 + t;            // 0..2047 groups of 4
    const int row = idx >> 4, c4 = (idx & 15) * 4;
    short4v val = *(const short4v*)&qsrc[(size_t)row*64 + c4];
    *(short4v*)&q_s[row*68 + c4] = val;
  }
  if (t < 64) pwr_s[t] = pwr[h*64 + t];
  __syncthreads();

  const int lm = lane & 15;
  const int dq = (lane >> 4) * 4;        // q8/2
  const int q8 = (lane >> 4) * 8;
  float4v acc[2][5];
  #pragma unroll
  for (int i = 0; i < 2; i++)
    #pragma unroll
    for (int j = 0; j < 5; j++) { float4v z = {0.f,0.f,0.f,0.f}; acc[i][j] = z; }

  #pragma unroll
  for (int ks = 0; ks < 4; ks++) {
    const int dbase = ks*16 + dq;
    float p[4];
    #pragma unroll
    for (int c = 0; c < 4; c++) p[c] = pwr_s[dbase + c];
    short8v a[2], b[5];
    #pragma unroll
    for (int i = 0; i < 2; i++) {
      const int row = wave*32 + i*16 + lm;
      short4v qv = *(const short4v*)&q_s[row*68 + dbase];
      short8v av;
      #pragma unroll
      for (int c = 0; c < 4; c++) {
        const float q = bf2f((ushort)qv[c]);
        const float aq = fabsf(q);
        float f = 0.f;
        if (aq > 0.f) f = exp2f(p[c] * log2f(aq));
        const short fb = (short)f2bf(f);
        av[2*c]   = (q > 0.f) ? fb : (short)0;
        av[2*c+1] = (q < 0.f) ? fb : (short)0;
      }
      a[i] = av;
    }
    #pragma unroll
    for (int j = 0; j < 5; j++)
      b[j] = *(const short8v*)&kv_s[(j*16 + lm)*128 + ks*32 + q8];
    #pragma unroll
    for (int i = 0; i < 2; i++)
      #pragma unroll
      for (int j = 0; j < 5; j++)
        acc[i][j] = mfma16(a[i], b[j], acc[i][j]);
  }

  const int rq = (lane >> 4) * 4;
  #pragma unroll
  for (int i = 0; i < 2; i++) {
    #pragma unroll
    for (int r = 0; r < 4; r++) {
      const int n = n0 + wave*32 + i*16 + rq + r;
      const float dsim = __shfl(acc[i][4][r], lane & 48);
      const float dopp = __shfl(acc[i][4][r], (lane & 48) | 1);
      const float zs = 1.f / (dsim + 1e-6f);
      const float zo = 1.f / (dopp + 1e-6f);
      if (n < NPOS) {
        ushort* orow = XO + (((size_t)bh * NPOS + n) << 6);
        #pragma unroll
        for (int j = 0; j < 4; j++)
          orow[j*16 + lm] = f2bf(acc[i][j][r] * ((j < 2) ? zs : zo));
      }
    }
  }
}

// ------- 5x5 depthwise conv + (xo+vd)*g -> combined bf16 natural -------
__global__ __launch_bounds__(256) void conv_combine_kernel(
    const ushort* __restrict__ Vb, const ushort* __restrict__ XO,
    const ushort* __restrict__ g, const float* __restrict__ dwc_w,
    const float* __restrict__ dwc_b, ushort* __restrict__ cmb)
{
  __shared__ ushort vs[6*60*64];   // 46080 B
  const int t = threadIdx.x;
  const int bh = blockIdx.y, b = bh >> 3, h = bh & 7;
  const int y0 = blockIdx.x * 2;
  for (int i = t; i < 5760; i += 256) {
    const int ry = i / 960;
    const int rem = i - ry * 960;
    const int xx = (rem >> 4) - 2;
    const int c4 = (rem & 15) * 4;
    const int yy = y0 - 2 + ry;
    short4v val = {0,0,0,0};
    if (yy >= 0 && yy < 56 && xx >= 0 && xx < 56)
      val = *(const short4v*)&Vb[(((size_t)bh*NPOS + yy*56 + xx) << 6) + c4];
    *(short4v*)&vs[ry*3840 + (rem >> 4)*64 + c4] = val;
  }
  __syncthreads();

  const int c = t & 63, xg = t >> 6;
  float w[25];
  #pragma unroll
  for (int i = 0; i < 25; i++) w[i] = dwc_w[c*25 + i];
  const float bias = dwc_b[c];

  #pragma unroll
  for (int y = 0; y < 2; y++) {
    float acc[14];
    #pragma unroll
    for (int xi = 0; xi < 14; xi++) acc[xi] = bias;
    #pragma unroll
    for (int ky = 0; ky < 5; ky++) {
      const ushort* row = &vs[(y + ky)*3840 + (xg*14)*64 + c];
      #pragma unroll
      for (int xl = 0; xl < 18; xl++) {
        const float val = bf2f(row[xl*64]);
        #pragma unroll
        for (int kx = 0; kx < 5; kx++) {
          const int xi = xl - kx;
          if (xi >= 0 && xi < 14)
            acc[xi] = fmaf(w[ky*5 + kx], val, acc[xi]);
        }
      }
    }
    const int yo = y0 + y;
    #pragma unroll
    for (int xi = 0; xi < 14; xi++) {
      const int n = yo*56 + xg*14 + xi;
      const float xov = bf2f(XO[(((size_t)bh*NPOS + n) << 6) + c]);
      const size_t nat = ((size_t)b*NPOS + n)*512 + h*64 + c;
      cmb[nat] = f2bf((xov + acc[xi]) * bf2f(g[nat]));
    }
  }
}

// ---------------- launch ----------------
extern "C" void kernel_launch(void* const* d_in, const int* in_sizes, int n_in,
                              void* d_out, int out_size, void* d_ws, size_t ws_size,
                              hipStream_t stream)
{
  const float* x       = (const float*)d_in[0];
  const float* qg_w    = (const float*)d_in[1];
  const float* kv_w    = (const float*)d_in[2];
  const float* proj_w  = (const float*)d_in[3];
  const float* proj_b  = (const float*)d_in[4];
  const float* pos_enc = (const float*)d_in[5];
  const float* scale_p = (const float*)d_in[6];
  const float* power_p = (const float*)d_in[7];
  const float* dwc_w   = (const float*)d_in[8];
  const float* dwc_b   = (const float*)d_in[9];
  float* out = (float*)d_out;

  const size_t MCs = (size_t)MROWS * 512;          // 25,690,112 elements
  ushort* xbf = (ushort*)d_ws;                     // x bf16 -> later cmb
  ushort* khm = xbf + MCs;                         // k head-major -> later XO
  ushort* vhm = khm + MCs;
  ushort* qhm = vhm + MCs;
  ushort* Kt  = qhm + MCs;                         // [128][80][128]
  ushort* wcat= Kt + (size_t)128*80*128;           // [2048][512]
  ushort* wpj = wcat + (size_t)2048*512;           // [512][512]
  float* pkv  = (float*)(wpj + (size_t)512*512);   // 4*128*8192
  float* pkm  = pkv + (size_t)RSPLIT*128*8192;
  float* scinv= pkm + (size_t)RSPLIT*128*128;
  float* pwr  = scinv + 512;
  const size_t need = (size_t)((char*)(pwr + 512) - (char*)d_ws);
  if (ws_size < need) return;

  ushort* XOb = khm;           // k dead after reduce_kv
  ushort* cmb = xbf;           // x dead after fused GEMM
  ushort* gbuf = (ushort*)out; // d_out low half; consumed before proj overwrites

  prep_kernel<<<1, 512, 0, stream>>>(scale_p, power_p, scinv, pwr);
  cvt_x_kernel<<<(int)(MCs/4/256), 256, 0, stream>>>(x, xbf);
  transpose_w_kernel<<<dim3(32,16), 256, 0, stream>>>(kv_w, wcat, 512, 1024);
  transpose_w_kernel<<<dim3(32,16), 256, 0, stream>>>(qg_w, wcat + (size_t)1024*512, 512, 1024);
  transpose_w_kernel<<<dim3(16,16), 256, 0, stream>>>(proj_w, wpj, 512, 512);

  gemm_feat_kernel<<<dim3(16, MROWS/128), 256, 0, stream>>>(
      xbf, wcat, scinv, pos_enc, khm, vhm, qhm, gbuf);
  reduce_kv_kernel<<<128*RSPLIT, 256, 0, stream>>>(khm, vhm, pwr, pkv, pkm);
  reduce_final_kernel<<<128, 256, 0, stream>>>(pkv, pkm, Kt);
  attn_mfma_kernel<<<dim3(25, 128), 256, 0, stream>>>(qhm, Kt, pwr, XOb);
  conv_combine_kernel<<<dim3(28, 128), 256, 0, stream>>>(vhm, XOb, gbuf, dwc_w, dwc_b, cmb);
  gemm_proj_kernel<<<dim3(4, MROWS/128), 256, 0, stream>>>(cmb, wpj, proj_b, out);
}